// Round 4
// baseline (392.835 us; speedup 1.0000x reference)
//
#include <hip/hip_runtime.h>

typedef _Float16 h8 __attribute__((ext_vector_type(8)));
typedef _Float16 h4 __attribute__((ext_vector_type(4)));
typedef float f4 __attribute__((ext_vector_type(4)));

#define MFMA16(a, b, c) __builtin_amdgcn_mfma_f32_16x16x32_f16((a), (b), (c), 0, 0, 0)
#define AS1 __attribute__((address_space(1)))
#define AS3 __attribute__((address_space(3)))

static __device__ __forceinline__ void load_lds16(const _Float16* g, _Float16* l) {
  // async DMA: 16B per lane, LDS dest = wave-uniform base + lane*16 [m97]
  __builtin_amdgcn_global_load_lds((const AS1 void*)g, (AS3 void*)l, 16, 0, 0);
}

// ---------------- fp32 -> fp16 elementwise convert ----------------
__global__ __launch_bounds__(256) void cvt_f32_f16(const float* __restrict__ in,
                                                   _Float16* __restrict__ out, int n) {
  int i = (blockIdx.x * 256 + threadIdx.x) * 4;
  if (i < n) {
    const float4 v = *(const float4*)(in + i);
    h4 o;
    o[0] = (_Float16)v.x; o[1] = (_Float16)v.y; o[2] = (_Float16)v.z; o[3] = (_Float16)v.w;
    *(h4*)(out + i) = o;
  }
}

// ---------------- transpose+convert: W[K][N] f32 -> Wt[N][K] f16 ----------------
__global__ __launch_bounds__(256) void transpose_cvt(const float* __restrict__ W,
                                                     _Float16* __restrict__ Wt, int K, int N) {
  __shared__ _Float16 t[64][66];
  int n0 = blockIdx.x * 64, k0 = blockIdx.y * 64;
  int c = threadIdx.x & 63, r0 = threadIdx.x >> 6;
  for (int i = 0; i < 16; i++) {
    int r = r0 * 16 + i;
    t[r][c] = (_Float16)W[(size_t)(k0 + r) * N + n0 + c];
  }
  __syncthreads();
  for (int i = 0; i < 16; i++) {
    int r = r0 * 16 + i;
    Wt[(size_t)(n0 + r) * K + k0 + c] = t[c][r];
  }
}

// ---------------- GEMM (128x128 tile, BK=32, async double-buffered): C = A @ Bt^T + bias --
// r0 structure (proven 43% MfmaUtil at 2 blocks/CU) with BK 64->32: staging LDS halves to
// 32 KiB; block LDS = 34816 B (epilogue bounce bound) -> 4 blocks/CU co-resident, i.e. 4
// waves/SIMD from 4 DIFFERENT blocks with decoupled barriers (m114 overlap mechanism, 2x r0).
// Single barrier per K-tile: DMA for tile T+1 issued right after the barrier into the back
// buffer; latency hidden by tile T's 16 MFMAs/wave + the other 3 blocks' work; drain lands
// at the NEXT barrier.
// BK=32 swizzle: stage granule g = c*256+tid -> row = g>>2, swz-chunk = g&3, source chunk
// = (tid&3)^((tid>>2)&3); read pc = quad^(l16&3)  (element-verified; min-cycle banks).
// MODE 0: QKV scatter epilogue via 128x136 LDS bounce; MODE 1: fp32 out.
template <int MODE>
__global__ __launch_bounds__(256, 4) void gemm_bt(const _Float16* __restrict__ A,
                                                  const _Float16* __restrict__ Bt,
                                                  const float* __restrict__ bias, int K,
                                                  _Float16* __restrict__ qp,
                                                  _Float16* __restrict__ kp,
                                                  _Float16* __restrict__ vtp,
                                                  float* __restrict__ outp, int N) {
  __shared__ __align__(16) _Float16 SH[17408];  // max(staging 2x8192, bounce 128x136=17408)
  const int m0 = blockIdx.y * 128, n0 = blockIdx.x * 128;
  const int tid = threadIdx.x;
  const int w = tid >> 6, lane = tid & 63, quad = lane >> 4, l16 = lane & 15;
  const int wm = (w >> 1) * 64, wn = (w & 1) * 64;

  // staging: thread tid -> base row tid>>2, source k-chunk (tid&3)^((tid>>2)&3)
  const int srow = tid >> 2;
  const int scol = ((tid & 3) ^ ((tid >> 2) & 3)) * 8;
  const _Float16* Ag = A + (size_t)(m0 + srow) * K + scol;
  const _Float16* Bg = Bt + (size_t)(n0 + srow) * K + scol;

  f4 acc[4][4] = {};
  const int NT = K >> 5;

  // buf b: A at b*8192, B at b*8192+4096 (f16 units); per round c (64 rows): +c*2048
#define STG(b, T)                                                              \
  {                                                                            \
    const size_t ko = (size_t)(T) * 32;                                        \
    load_lds16(Ag + ko, SH + (b) * 8192 + w * 512);                            \
    load_lds16(Ag + ko + (size_t)64 * K, SH + (b) * 8192 + 2048 + w * 512);    \
    load_lds16(Bg + ko, SH + (b) * 8192 + 4096 + w * 512);                     \
    load_lds16(Bg + ko + (size_t)64 * K, SH + (b) * 8192 + 6144 + w * 512);    \
  }

  STG(0, 0);  // prologue: tile 0 -> buf 0
  for (int T = 0; T < NT; ++T) {
    const int cur = T & 1;
    __syncthreads();  // buf[cur] DMA drained (all waves) + prev readers of buf[cur^1] done
    if (T + 1 < NT) STG(cur ^ 1, T + 1);
    const _Float16* As = SH + cur * 8192;
    const _Float16* Bs = As + 4096;
    h8 af[4], bf[4];
    const int pc8 = (quad ^ (l16 & 3)) * 8;
#pragma unroll
    for (int mi = 0; mi < 4; mi++) {
      const int r = wm + mi * 16 + l16;
      af[mi] = *(const h8*)(&As[r * 32 + pc8]);
    }
#pragma unroll
    for (int ni = 0; ni < 4; ni++) {
      const int r = wn + ni * 16 + l16;
      bf[ni] = *(const h8*)(&Bs[r * 32 + pc8]);
    }
    __builtin_amdgcn_s_setprio(1);
#pragma unroll
    for (int mi = 0; mi < 4; mi++)
#pragma unroll
      for (int ni = 0; ni < 4; ni++) acc[mi][ni] = MFMA16(af[mi], bf[ni], acc[mi][ni]);
    __builtin_amdgcn_s_setprio(0);
  }
#undef STG

  // ---- Epilogue. C element (row = quad*4+r, col = l16) per 16x16 tile [m89-verified]. ----
  if constexpr (MODE == 0) {
    __syncthreads();
    _Float16* U = SH;  // 128 x 136 bounce tile (34816 B)
    const int which = n0 >> 11, hh = (n0 >> 7) & 15;
    const int bq = m0 >> 11, ms = m0 & 2047;
    const size_t hb = (size_t)bq * 16 + hh;
    if (which == 2) {
      for (int mi = 0; mi < 4; mi++)
        for (int ni = 0; ni < 4; ni++) {
          int d = wn + ni * 16 + l16;
          int s0 = wm + mi * 16 + quad * 4;
          float bv = bias[n0 + d];
          h4 pack;
          for (int r = 0; r < 4; r++) pack[r] = (_Float16)(acc[mi][ni][r] + bv);
          *(h4*)(&U[d * 136 + s0]) = pack;
        }
    } else {
      for (int mi = 0; mi < 4; mi++)
        for (int ni = 0; ni < 4; ni++) {
          int d = wn + ni * 16 + l16;
          float bv = bias[n0 + d];
          for (int r = 0; r < 4; r++) {
            int s = wm + mi * 16 + quad * 4 + r;
            U[s * 136 + d] = (_Float16)(acc[mi][ni][r] + bv);
          }
        }
    }
    __syncthreads();
    if (which == 2) {
      _Float16* dst = vtp + hb * (size_t)(128 * 2048) + ms;
#pragma unroll
      for (int i = 0; i < 8; i++) {
        int f = i * 256 + tid, row = f >> 4, ch = f & 15;
        *(h8*)(dst + (size_t)row * 2048 + ch * 8) = *(h8*)(&U[row * 136 + ch * 8]);
      }
    } else {
      _Float16* dst = (which == 0 ? qp : kp) + (hb * 2048 + ms) * (size_t)128;
#pragma unroll
      for (int i = 0; i < 8; i++) {
        int f = i * 256 + tid, row = f >> 4, ch = f & 15;
        *(h8*)(dst + (size_t)row * 128 + ch * 8) = *(h8*)(&U[row * 136 + ch * 8]);
      }
    }
  } else {
    for (int mi = 0; mi < 4; mi++)
      for (int ni = 0; ni < 4; ni++) {
        int gm_base = m0 + wm + mi * 16 + quad * 4;
        int gn = n0 + wn + ni * 16 + l16;
        float bv = bias[gn];
        for (int r = 0; r < 4; r++)
          outp[(size_t)(gm_base + r) * N + gn] = acc[mi][ni][r] + bv;
      }
  }
}

// ---------------- fused causal ALiBi attention ----------------
// grid (32 bh, 16 px): 512 uniform blocks (2/CU, 2 waves/SIMD); same-(b,h) blocks share an
// XCD (linear id mod 8 = bh mod 8) so K/V re-reads hit that XCD's L2.
// Block: 4 waves x 16 q-rows = 64-row tile; pairs {31-px, px} -> 33 j-iters each.
// K/V async-DMA double-buffered (1 barrier/iter, latency hidden under compute).
// ALiBi as column bias slope*j (row term -slope*i cancels in softmax); causal mask only on
// the diagonal tile. Row-sum l via a ones-column MFMA tile (o[8]).
__global__ __launch_bounds__(256, 2) void attn_kernel(const _Float16* __restrict__ Q,
                                                      const _Float16* __restrict__ Kg,
                                                      const _Float16* __restrict__ Vt,
                                                      _Float16* __restrict__ ctx) {
  __shared__ _Float16 Ks[2][8192];   // 64 rows x 128, 16B-chunk XOR swizzle p = lc ^ (row&7)
  __shared__ _Float16 Vs[2][8192];   // 128 rows x 64, same swizzle
  __shared__ _Float16 Vones[1088];   // [16][68]: row 0 = ones (l-accumulator B-tile)
  __shared__ _Float16 Pl[4][16 * 68];  // per-wave P round-trip; stride 68 -> conflict-free

  const int bh = blockIdx.x, px = blockIdx.y;
  const int b = bh >> 4, h = bh & 15;
  const int tid = threadIdx.x, w = tid >> 6, lane = tid & 63, quad = lane >> 4, l16 = lane & 15;
  const size_t hbo = (size_t)bh * (2048 * 128);
  const _Float16* Qh = Q + hbo;
  const _Float16* Kh = Kg + hbo;
  const _Float16* Vh = Vt + hbo;
  const float slope = exp2f(-0.5f * (float)h);
  const float L2E = 1.44269504088896f;
  const float NEG = -3.0e38f;

  for (int i = tid; i < 1088; i += 256) Vones[i] = (_Float16)0.f;
  if (tid < 64) Vones[tid] = (_Float16)1.f;  // row 0, cols 0..63

  float cj[4];
  for (int jf = 0; jf < 4; jf++) cj[jf] = slope * (float)(jf * 16 + l16);

  // staging constants: K slot s=c*64+lane -> row=4c+quad, lc=l16^((c&1)*4+quad)
  //                    V slot s=c*64+lane -> row=8c+(lane>>3), lc=(lane&7)^(lane>>3)
  const int kle = (l16 ^ quad) * 8, klo = kle ^ 32;
  const int lq = lane >> 3, vlc = ((lane & 7) ^ lq) * 8;

  for (int phase = 0; phase < 2; phase++) {
    const int t = phase ? px : 31 - px;
    const int qbase = t * 64 + w * 16;

    h8 aq[4];  // Q A-frags: A[m=l16][k=quad*8+j] [m120-verified]
#pragma unroll
    for (int t4 = 0; t4 < 4; t4++)
      aq[t4] = *(const h8*)(Qh + (size_t)(qbase + l16) * 128 + t4 * 32 + quad * 8);

    f4 o[9] = {};  // o[0..7] = output tiles, o[8] = row-sum (ones column)
    float m_i[4];
    for (int r = 0; r < 4; r++) m_i[r] = NEG;

    const int jtiles = t + 1;
    __syncthreads();  // previous phase's buffer readers (and Vones init) done
    // stage tile 0 -> buf 0 (waves 0,1: K; waves 2,3: V)
    if (w < 2) {
      const _Float16* kb = Kh + (size_t)(32 * w + quad) * 128;
      _Float16* dst = &Ks[0][w * 4096];
#pragma unroll
      for (int cc = 0; cc < 8; cc++)
        load_lds16(kb + (size_t)(4 * cc) * 128 + ((cc & 1) ? klo : kle), dst + cc * 512);
    } else {
      const _Float16* vb = Vh + (size_t)(64 * (w - 2) + lq) * 2048 + vlc;
      _Float16* dst = &Vs[0][(w - 2) * 4096];
#pragma unroll
      for (int cc = 0; cc < 8; cc++) load_lds16(vb + (size_t)(8 * cc) * 2048, dst + cc * 512);
    }

    for (int jt = 0; jt < jtiles; jt++) {
      const int j0 = jt * 64, cur = jt & 1;
      __syncthreads();  // buf[cur] staged (each wave drains vmcnt before barrier)
      if (jt + 1 < jtiles) {  // async-stage next tile into back buffer
        const int nj0 = j0 + 64, nb = cur ^ 1;
        if (w < 2) {
          const _Float16* kb = Kh + (size_t)(nj0 + 32 * w + quad) * 128;
          _Float16* dst = &Ks[nb][w * 4096];
#pragma unroll
          for (int cc = 0; cc < 8; cc++)
            load_lds16(kb + (size_t)(4 * cc) * 128 + ((cc & 1) ? klo : kle), dst + cc * 512);
        } else {
          const _Float16* vb = Vh + (size_t)(64 * (w - 2) + lq) * 2048 + nj0 + vlc;
          _Float16* dst = &Vs[nb][(w - 2) * 4096];
#pragma unroll
          for (int cc = 0; cc < 8; cc++) load_lds16(vb + (size_t)(8 * cc) * 2048, dst + cc * 512);
        }
      }
      // S = Q K^T (B-frag from swizzled Ks)
      f4 sc[4] = {};
#pragma unroll
      for (int jf = 0; jf < 4; jf++) {
        const int row = jf * 16 + l16;
#pragma unroll
        for (int t4 = 0; t4 < 4; t4++) {
          const int p = (t4 * 4 + quad) ^ (l16 & 7);
          h8 bk = *(const h8*)(&Ks[cur][row * 128 + p * 8]);
          sc[jf] = MFMA16(aq[t4], bk, sc[jf]);
        }
      }
      // ALiBi column bias
      const float bj0 = slope * (float)j0;
#pragma unroll
      for (int jf = 0; jf < 4; jf++) {
        const float cb = bj0 + cj[jf];
#pragma unroll
        for (int r = 0; r < 4; r++) sc[jf][r] += cb;
      }
      if (jt == jtiles - 1) {  // diagonal tile: causal mask
#pragma unroll
        for (int jf = 0; jf < 4; jf++) {
          const int j = j0 + jf * 16 + l16;
#pragma unroll
          for (int r = 0; r < 4; r++)
            if (j > qbase + quad * 4 + r) sc[jf][r] = NEG;
        }
      }
      // online softmax (max only; sum rides in o[8])
      float m_new[4], alpha[4];
#pragma unroll
      for (int r = 0; r < 4; r++) {
        float v = fmaxf(fmaxf(sc[0][r], sc[1][r]), fmaxf(sc[2][r], sc[3][r]));
        v = fmaxf(v, __shfl_xor(v, 1));
        v = fmaxf(v, __shfl_xor(v, 2));
        v = fmaxf(v, __shfl_xor(v, 4));
        v = fmaxf(v, __shfl_xor(v, 8));
        m_new[r] = fmaxf(m_i[r], v);
        alpha[r] = exp2f((m_i[r] - m_new[r]) * L2E);
        m_i[r] = m_new[r];
      }
#pragma unroll
      for (int jf = 0; jf < 4; jf++)
#pragma unroll
        for (int r = 0; r < 4; r++) sc[jf][r] = exp2f((sc[jf][r] - m_new[r]) * L2E);
#pragma unroll
      for (int nt = 0; nt < 9; nt++)
#pragma unroll
        for (int r = 0; r < 4; r++) o[nt][r] *= alpha[r];
      // P: C-layout -> A-layout via per-wave LDS (stride 68: conflict-free writes)
#pragma unroll
      for (int jf = 0; jf < 4; jf++)
#pragma unroll
        for (int r = 0; r < 4; r++)
          Pl[w][(quad * 4 + r) * 68 + jf * 16 + l16] = (_Float16)sc[jf][r];
      asm volatile("s_waitcnt lgkmcnt(0)" ::: "memory");
      h8 ap0 = *(const h8*)(&Pl[w][l16 * 68 + quad * 8]);
      h8 ap1 = *(const h8*)(&Pl[w][l16 * 68 + 32 + quad * 8]);
      // O += P V (B-frag from swizzled Vs) + ones-tile for l
#pragma unroll
      for (int nt = 0; nt < 8; nt++) {
        const int row = nt * 16 + l16;
        const int p0 = quad ^ (l16 & 7), p1 = (4 + quad) ^ (l16 & 7);
        h8 bv0 = *(const h8*)(&Vs[cur][row * 64 + p0 * 8]);
        h8 bv1 = *(const h8*)(&Vs[cur][row * 64 + p1 * 8]);
        o[nt] = MFMA16(ap0, bv0, o[nt]);
        o[nt] = MFMA16(ap1, bv1, o[nt]);
      }
      {
        h8 b0 = *(const h8*)(&Vones[l16 * 68 + quad * 8]);
        h8 b1 = *(const h8*)(&Vones[l16 * 68 + 32 + quad * 8]);
        o[8] = MFMA16(ap0, b0, o[8]);
        o[8] = MFMA16(ap1, b1, o[8]);
      }
    }

    // epilogue: l = o[8] col 0 (broadcast within quad), normalize, write ctx
#pragma unroll
    for (int r = 0; r < 4; r++) {
      float lsum = __shfl(o[8][r], lane & 48);
      float inv = 1.0f / lsum;
      const int i = qbase + quad * 4 + r;
      const size_t row = (size_t)b * 2048 + i;
#pragma unroll
      for (int nt = 0; nt < 8; nt++)
        ctx[row * 2048 + h * 128 + nt * 16 + l16] = (_Float16)(o[nt][r] * inv);
    }
  }
}

extern "C" void kernel_launch(void* const* d_in, const int* in_sizes, int n_in, void* d_out,
                              int out_size, void* d_ws, size_t ws_size, hipStream_t stream) {
  const float* x = (const float*)d_in[0];      // [2,2048,2048]
  const float* qkv_w = (const float*)d_in[1];  // [2048,6144]
  const float* qkv_b = (const float*)d_in[2];  // [6144]
  const float* out_w = (const float*)d_in[3];  // [2048,2048]
  const float* out_b = (const float*)d_in[4];  // [2048]
  float* out = (float*)d_out;                  // [4096,2048] f32

  char* ws = (char*)d_ws;
  if (ws_size < 117440512u) return;  // need 112 MiB
  _Float16* xb  = (_Float16*)(ws + 0);          // 16 MiB  [4096][2048]
  _Float16* wqt = (_Float16*)(ws + 16777216);   // 24 MiB  [6144][2048]
  _Float16* wot = (_Float16*)(ws + 41943040);   // 8 MiB   [2048][2048]
  _Float16* q   = (_Float16*)(ws + 50331648);   // 16 MiB  [b,h,s,d]
  _Float16* k   = (_Float16*)(ws + 67108864);   // 16 MiB  [b,h,s,d]
  _Float16* vt  = (_Float16*)(ws + 83886080);   // 16 MiB  [b,h,d,s]
  _Float16* ctx = (_Float16*)(ws + 100663296);  // 16 MiB  [4096][2048]

  cvt_f32_f16<<<8192, 256, 0, stream>>>(x, xb, 8388608);
  transpose_cvt<<<dim3(96, 32), 256, 0, stream>>>(qkv_w, wqt, 2048, 6144);
  transpose_cvt<<<dim3(32, 32), 256, 0, stream>>>(out_w, wot, 2048, 2048);
  gemm_bt<0><<<dim3(48, 32), 256, 0, stream>>>(xb, wqt, qkv_b, 2048, q, k, vt, nullptr, 6144);
  attn_kernel<<<dim3(32, 16), 256, 0, stream>>>(q, k, vt, ctx);
  gemm_bt<1><<<dim3(16, 32), 256, 0, stream>>>(ctx, wot, out_b, 2048, nullptr, nullptr, nullptr,
                                               out, 2048);
}

// Round 5
// 369.496 us; speedup vs baseline: 1.0632x; 1.0632x over previous
//
#include <hip/hip_runtime.h>

typedef _Float16 h8 __attribute__((ext_vector_type(8)));
typedef _Float16 h4 __attribute__((ext_vector_type(4)));
typedef float f4 __attribute__((ext_vector_type(4)));

#define MFMA16(a, b, c) __builtin_amdgcn_mfma_f32_16x16x32_f16((a), (b), (c), 0, 0, 0)
#define AS1 __attribute__((address_space(1)))
#define AS3 __attribute__((address_space(3)))

static __device__ __forceinline__ void load_lds16(const _Float16* g, _Float16* l) {
  // async DMA: 16B per lane, LDS dest = wave-uniform base + lane*16 [m97]
  __builtin_amdgcn_global_load_lds((const AS1 void*)g, (AS3 void*)l, 16, 0, 0);
}

// ---------------- fused prep: qkv_w transpose | out_w transpose | x convert ----------------
// One launch replaces three: removes 2 launch gaps and overlaps the three memory-bound
// tasks' ramp/drain tails. Transpose write path vectorized (h8 16-B stores, 128 B per 8
// lanes) instead of the old scalar 2-B stores (G13).
static __device__ __forceinline__ void tr_tile(const float* __restrict__ W,
                                               _Float16* __restrict__ Wt, int K, int N, int n0,
                                               int k0, int tid, _Float16 (*t)[66]) {
  const int c = tid & 63, r0_ = tid >> 6;
#pragma unroll
  for (int i = 0; i < 16; i++) {
    int r = r0_ * 16 + i;
    t[r][c] = (_Float16)W[(size_t)(k0 + r) * N + n0 + c];
  }
  __syncthreads();
  const int x8 = tid & 7, nl = tid >> 3;  // k-chunk, n-row
#pragma unroll
  for (int i = 0; i < 2; i++) {
    const int n = nl + 32 * i;
    h8 v;
#pragma unroll
    for (int j = 0; j < 8; j++) v[j] = t[x8 * 8 + j][n];
    *(h8*)(&Wt[(size_t)(n0 + n) * K + k0 + x8 * 8]) = v;
  }
}

__global__ __launch_bounds__(256) void prep(const float* __restrict__ x,
                                            _Float16* __restrict__ xb,
                                            const float* __restrict__ qkv_w,
                                            _Float16* __restrict__ wqt,
                                            const float* __restrict__ out_w,
                                            _Float16* __restrict__ wot) {
  __shared__ _Float16 t[64][66];
  const int bid = blockIdx.x, tid = threadIdx.x;
  if (bid < 3072) {  // qkv_w [2048][6144] -> wqt [6144][2048]
    tr_tile(qkv_w, wqt, 2048, 6144, (bid % 96) * 64, (bid / 96) * 64, tid, t);
  } else if (bid < 4096) {  // out_w [2048][2048] -> wot [2048][2048]
    const int b2 = bid - 3072;
    tr_tile(out_w, wot, 2048, 2048, (b2 & 31) * 64, (b2 >> 5) * 64, tid, t);
  } else {  // x convert: 8388608 floats = 2097152 float4, blocks 4096..6143 x 1024 each
    const size_t base = (size_t)(bid - 4096) * 1024;
#pragma unroll
    for (int u = 0; u < 4; u++) {
      const size_t i4 = base + u * 256 + tid;
      const float4 v = *(const float4*)(x + i4 * 4);
      h4 o;
      o[0] = (_Float16)v.x; o[1] = (_Float16)v.y; o[2] = (_Float16)v.z; o[3] = (_Float16)v.w;
      *(h4*)(xb + i4 * 4) = o;
    }
  }
}

// ---------------- GEMM (BK=64, async double-buffered): C = A @ Bt^T + bias ----------------
// r0-exact (best measured: 110 us, MfmaUtil 43%, ~0 conflicts). Single barrier per K-iter:
// DMA for tile k+1 issued right after the barrier into the back buffer; latency hidden by
// tile k's 32 MFMAs; drain lands at the NEXT barrier. 2 blocks/CU -> decoupled barrier
// domains (m114 overlap). XOR chunk swizzle (proven 0 conflicts). MODE 0: QKV scatter via
// LDS bounce; MODE 1: fp32 out.
template <int MODE>
__global__ __launch_bounds__(256, 2) void gemm_bt(const _Float16* __restrict__ A,
                                               const _Float16* __restrict__ Bt,
                                               const float* __restrict__ bias, int K,
                                               _Float16* __restrict__ qp, _Float16* __restrict__ kp,
                                               _Float16* __restrict__ vtp, float* __restrict__ outp,
                                               int N) {
  __shared__ _Float16 LDS[2][16384];  // [buf][ As 8192 | Bs 8192 ], 64 KB total
  const int m0 = blockIdx.y * 128, n0 = blockIdx.x * 128;
  const int tid = threadIdx.x;
  const int w = tid >> 6, lane = tid & 63, quad = lane >> 4, l16 = lane & 15;
  const int wm = (w >> 1) * 64, wn = (w & 1) * 64;

  const int lc8 = (((lane & 7) ^ (lane >> 3)) * 8);  // swizzled k-offset (f16)
  const int rb = w * 32 + (lane >> 3);
  const _Float16* ap0 = A + (size_t)(m0 + rb) * K + lc8;
  const _Float16* bp0 = Bt + (size_t)(n0 + rb) * K + lc8;

  f4 acc[4][4] = {};
  // prologue: stage k=0 into buf 0
#pragma unroll
  for (int i = 0; i < 4; i++) {
    load_lds16(ap0 + (size_t)(i * 8) * K, &LDS[0][w * 2048 + i * 512]);
    load_lds16(bp0 + (size_t)(i * 8) * K, &LDS[0][8192 + w * 2048 + i * 512]);
  }
  for (int k0 = 0; k0 < K; k0 += 64) {
    const int cur = (k0 >> 6) & 1;
    __syncthreads();  // buf[cur] DMA drained (all waves) + prev readers of buf[cur^1] done
    if (k0 + 64 < K) {
      const int nb = cur ^ 1;
#pragma unroll
      for (int i = 0; i < 4; i++) {
        load_lds16(ap0 + (size_t)(i * 8) * K + k0 + 64, &LDS[nb][w * 2048 + i * 512]);
        load_lds16(bp0 + (size_t)(i * 8) * K + k0 + 64, &LDS[nb][8192 + w * 2048 + i * 512]);
      }
    }
    const _Float16* As = &LDS[cur][0];
    const _Float16* Bs = &LDS[cur][8192];
#pragma unroll
    for (int ks = 0; ks < 2; ks++) {
      h8 af[4], bf[4];
      for (int mi = 0; mi < 4; mi++) {
        int r = wm + mi * 16 + l16;
        int pc = (ks * 4 + quad) ^ (l16 & 7);
        af[mi] = *(const h8*)(&As[r * 64 + pc * 8]);
      }
      for (int ni = 0; ni < 4; ni++) {
        int r = wn + ni * 16 + l16;
        int pc = (ks * 4 + quad) ^ (l16 & 7);
        bf[ni] = *(const h8*)(&Bs[r * 64 + pc * 8]);
      }
      for (int mi = 0; mi < 4; mi++)
        for (int ni = 0; ni < 4; ni++) acc[mi][ni] = MFMA16(af[mi], bf[ni], acc[mi][ni]);
    }
  }

  // ---- Epilogue. C element (row = quad*4+r, col = l16) per 16x16 tile [m89-verified]. ----
  if constexpr (MODE == 0) {
    __syncthreads();
    _Float16* U = &LDS[0][0];  // 128 x 136 bounce tile (34816 B <= 64 KB)
    const int which = n0 >> 11, hh = (n0 >> 7) & 15;
    const int bq = m0 >> 11, ms = m0 & 2047;
    const size_t hb = (size_t)bq * 16 + hh;
    if (which == 2) {
      for (int mi = 0; mi < 4; mi++)
        for (int ni = 0; ni < 4; ni++) {
          int d = wn + ni * 16 + l16;
          int s0 = wm + mi * 16 + quad * 4;
          float bv = bias[n0 + d];
          h4 pack;
          for (int r = 0; r < 4; r++) pack[r] = (_Float16)(acc[mi][ni][r] + bv);
          *(h4*)(&U[d * 136 + s0]) = pack;
        }
    } else {
      for (int mi = 0; mi < 4; mi++)
        for (int ni = 0; ni < 4; ni++) {
          int d = wn + ni * 16 + l16;
          float bv = bias[n0 + d];
          for (int r = 0; r < 4; r++) {
            int s = wm + mi * 16 + quad * 4 + r;
            U[s * 136 + d] = (_Float16)(acc[mi][ni][r] + bv);
          }
        }
    }
    __syncthreads();
    if (which == 2) {
      _Float16* dst = vtp + hb * (size_t)(128 * 2048) + ms;
#pragma unroll
      for (int i = 0; i < 8; i++) {
        int f = i * 256 + tid, row = f >> 4, ch = f & 15;
        *(h8*)(dst + (size_t)row * 2048 + ch * 8) = *(h8*)(&U[row * 136 + ch * 8]);
      }
    } else {
      _Float16* dst = (which == 0 ? qp : kp) + (hb * 2048 + ms) * (size_t)128;
#pragma unroll
      for (int i = 0; i < 8; i++) {
        int f = i * 256 + tid, row = f >> 4, ch = f & 15;
        *(h8*)(dst + (size_t)row * 128 + ch * 8) = *(h8*)(&U[row * 136 + ch * 8]);
      }
    }
  } else {
    for (int mi = 0; mi < 4; mi++)
      for (int ni = 0; ni < 4; ni++) {
        int gm_base = m0 + wm + mi * 16 + quad * 4;
        int gn = n0 + wn + ni * 16 + l16;
        float bv = bias[gn];
        for (int r = 0; r < 4; r++)
          outp[(size_t)(gm_base + r) * N + gn] = acc[mi][ni][r] + bv;
      }
  }
}

// ---------------- fused causal ALiBi attention ----------------
// grid (32 bh, 16 px): 512 uniform blocks (2/CU, 2 waves/SIMD); same-(b,h) blocks share an
// XCD (linear id mod 8 = bh mod 8) so K/V re-reads hit that XCD's L2.
// Block: 4 waves x 16 q-rows = 64-row tile; pairs {31-px, px} -> 33 j-iters each.
// K/V async-DMA double-buffered (1 barrier/iter, latency hidden under compute).
// ALiBi as column bias slope*j (row term -slope*i cancels in softmax); causal mask only on
// the diagonal tile. Row-sum l via a ones-column MFMA tile (o[8]).
__global__ __launch_bounds__(256, 2) void attn_kernel(const _Float16* __restrict__ Q,
                                                      const _Float16* __restrict__ Kg,
                                                      const _Float16* __restrict__ Vt,
                                                      _Float16* __restrict__ ctx) {
  __shared__ _Float16 Ks[2][8192];   // 64 rows x 128, 16B-chunk XOR swizzle p = lc ^ (row&7)
  __shared__ _Float16 Vs[2][8192];   // 128 rows x 64, same swizzle
  __shared__ _Float16 Vones[1088];   // [16][68]: row 0 = ones (l-accumulator B-tile)
  __shared__ _Float16 Pl[4][16 * 68];  // per-wave P round-trip; stride 68 -> conflict-free

  const int bh = blockIdx.x, px = blockIdx.y;
  const int b = bh >> 4, h = bh & 15;
  const int tid = threadIdx.x, w = tid >> 6, lane = tid & 63, quad = lane >> 4, l16 = lane & 15;
  const size_t hbo = (size_t)bh * (2048 * 128);
  const _Float16* Qh = Q + hbo;
  const _Float16* Kh = Kg + hbo;
  const _Float16* Vh = Vt + hbo;
  const float slope = exp2f(-0.5f * (float)h);
  const float L2E = 1.44269504088896f;
  const float NEG = -3.0e38f;

  for (int i = tid; i < 1088; i += 256) Vones[i] = (_Float16)0.f;
  if (tid < 64) Vones[tid] = (_Float16)1.f;  // row 0, cols 0..63

  float cj[4];
  for (int jf = 0; jf < 4; jf++) cj[jf] = slope * (float)(jf * 16 + l16);

  // staging constants: K slot s=c*64+lane -> row=4c+quad, lc=l16^((c&1)*4+quad)
  //                    V slot s=c*64+lane -> row=8c+(lane>>3), lc=(lane&7)^(lane>>3)
  const int kle = (l16 ^ quad) * 8, klo = kle ^ 32;
  const int lq = lane >> 3, vlc = ((lane & 7) ^ lq) * 8;

  for (int phase = 0; phase < 2; phase++) {
    const int t = phase ? px : 31 - px;
    const int qbase = t * 64 + w * 16;

    h8 aq[4];  // Q A-frags: A[m=l16][k=quad*8+j] [m120-verified]
#pragma unroll
    for (int t4 = 0; t4 < 4; t4++)
      aq[t4] = *(const h8*)(Qh + (size_t)(qbase + l16) * 128 + t4 * 32 + quad * 8);

    f4 o[9] = {};  // o[0..7] = output tiles, o[8] = row-sum (ones column)
    float m_i[4];
    for (int r = 0; r < 4; r++) m_i[r] = NEG;

    const int jtiles = t + 1;
    __syncthreads();  // previous phase's buffer readers (and Vones init) done
    // stage tile 0 -> buf 0 (waves 0,1: K; waves 2,3: V)
    if (w < 2) {
      const _Float16* kb = Kh + (size_t)(32 * w + quad) * 128;
      _Float16* dst = &Ks[0][w * 4096];
#pragma unroll
      for (int cc = 0; cc < 8; cc++)
        load_lds16(kb + (size_t)(4 * cc) * 128 + ((cc & 1) ? klo : kle), dst + cc * 512);
    } else {
      const _Float16* vb = Vh + (size_t)(64 * (w - 2) + lq) * 2048 + vlc;
      _Float16* dst = &Vs[0][(w - 2) * 4096];
#pragma unroll
      for (int cc = 0; cc < 8; cc++) load_lds16(vb + (size_t)(8 * cc) * 2048, dst + cc * 512);
    }

    for (int jt = 0; jt < jtiles; jt++) {
      const int j0 = jt * 64, cur = jt & 1;
      __syncthreads();  // buf[cur] staged (each wave drains vmcnt before barrier)
      if (jt + 1 < jtiles) {  // async-stage next tile into back buffer
        const int nj0 = j0 + 64, nb = cur ^ 1;
        if (w < 2) {
          const _Float16* kb = Kh + (size_t)(nj0 + 32 * w + quad) * 128;
          _Float16* dst = &Ks[nb][w * 4096];
#pragma unroll
          for (int cc = 0; cc < 8; cc++)
            load_lds16(kb + (size_t)(4 * cc) * 128 + ((cc & 1) ? klo : kle), dst + cc * 512);
        } else {
          const _Float16* vb = Vh + (size_t)(64 * (w - 2) + lq) * 2048 + nj0 + vlc;
          _Float16* dst = &Vs[nb][(w - 2) * 4096];
#pragma unroll
          for (int cc = 0; cc < 8; cc++) load_lds16(vb + (size_t)(8 * cc) * 2048, dst + cc * 512);
        }
      }
      // S = Q K^T (B-frag from swizzled Ks)
      f4 sc[4] = {};
#pragma unroll
      for (int jf = 0; jf < 4; jf++) {
        const int row = jf * 16 + l16;
#pragma unroll
        for (int t4 = 0; t4 < 4; t4++) {
          const int p = (t4 * 4 + quad) ^ (l16 & 7);
          h8 bk = *(const h8*)(&Ks[cur][row * 128 + p * 8]);
          sc[jf] = MFMA16(aq[t4], bk, sc[jf]);
        }
      }
      // ALiBi column bias
      const float bj0 = slope * (float)j0;
#pragma unroll
      for (int jf = 0; jf < 4; jf++) {
        const float cb = bj0 + cj[jf];
#pragma unroll
        for (int r = 0; r < 4; r++) sc[jf][r] += cb;
      }
      if (jt == jtiles - 1) {  // diagonal tile: causal mask
#pragma unroll
        for (int jf = 0; jf < 4; jf++) {
          const int j = j0 + jf * 16 + l16;
#pragma unroll
          for (int r = 0; r < 4; r++)
            if (j > qbase + quad * 4 + r) sc[jf][r] = NEG;
        }
      }
      // online softmax (max only; sum rides in o[8])
      float m_new[4], alpha[4];
#pragma unroll
      for (int r = 0; r < 4; r++) {
        float v = fmaxf(fmaxf(sc[0][r], sc[1][r]), fmaxf(sc[2][r], sc[3][r]));
        v = fmaxf(v, __shfl_xor(v, 1));
        v = fmaxf(v, __shfl_xor(v, 2));
        v = fmaxf(v, __shfl_xor(v, 4));
        v = fmaxf(v, __shfl_xor(v, 8));
        m_new[r] = fmaxf(m_i[r], v);
        alpha[r] = exp2f((m_i[r] - m_new[r]) * L2E);
        m_i[r] = m_new[r];
      }
#pragma unroll
      for (int jf = 0; jf < 4; jf++)
#pragma unroll
        for (int r = 0; r < 4; r++) sc[jf][r] = exp2f((sc[jf][r] - m_new[r]) * L2E);
#pragma unroll
      for (int nt = 0; nt < 9; nt++)
#pragma unroll
        for (int r = 0; r < 4; r++) o[nt][r] *= alpha[r];
      // P: C-layout -> A-layout via per-wave LDS (stride 68: conflict-free writes)
#pragma unroll
      for (int jf = 0; jf < 4; jf++)
#pragma unroll
        for (int r = 0; r < 4; r++)
          Pl[w][(quad * 4 + r) * 68 + jf * 16 + l16] = (_Float16)sc[jf][r];
      asm volatile("s_waitcnt lgkmcnt(0)" ::: "memory");
      h8 ap0 = *(const h8*)(&Pl[w][l16 * 68 + quad * 8]);
      h8 ap1 = *(const h8*)(&Pl[w][l16 * 68 + 32 + quad * 8]);
      // O += P V (B-frag from swizzled Vs) + ones-tile for l
#pragma unroll
      for (int nt = 0; nt < 8; nt++) {
        const int row = nt * 16 + l16;
        const int p0 = quad ^ (l16 & 7), p1 = (4 + quad) ^ (l16 & 7);
        h8 bv0 = *(const h8*)(&Vs[cur][row * 64 + p0 * 8]);
        h8 bv1 = *(const h8*)(&Vs[cur][row * 64 + p1 * 8]);
        o[nt] = MFMA16(ap0, bv0, o[nt]);
        o[nt] = MFMA16(ap1, bv1, o[nt]);
      }
      {
        h8 b0 = *(const h8*)(&Vones[l16 * 68 + quad * 8]);
        h8 b1 = *(const h8*)(&Vones[l16 * 68 + 32 + quad * 8]);
        o[8] = MFMA16(ap0, b0, o[8]);
        o[8] = MFMA16(ap1, b1, o[8]);
      }
    }

    // epilogue: l = o[8] col 0 (broadcast within quad), normalize, write ctx
#pragma unroll
    for (int r = 0; r < 4; r++) {
      float lsum = __shfl(o[8][r], lane & 48);
      float inv = 1.0f / lsum;
      const int i = qbase + quad * 4 + r;
      const size_t row = (size_t)b * 2048 + i;
#pragma unroll
      for (int nt = 0; nt < 8; nt++)
        ctx[row * 2048 + h * 128 + nt * 16 + l16] = (_Float16)(o[nt][r] * inv);
    }
  }
}

extern "C" void kernel_launch(void* const* d_in, const int* in_sizes, int n_in, void* d_out,
                              int out_size, void* d_ws, size_t ws_size, hipStream_t stream) {
  const float* x = (const float*)d_in[0];      // [2,2048,2048]
  const float* qkv_w = (const float*)d_in[1];  // [2048,6144]
  const float* qkv_b = (const float*)d_in[2];  // [6144]
  const float* out_w = (const float*)d_in[3];  // [2048,2048]
  const float* out_b = (const float*)d_in[4];  // [2048]
  float* out = (float*)d_out;                  // [4096,2048] f32

  char* ws = (char*)d_ws;
  if (ws_size < 117440512u) return;  // need 112 MiB
  _Float16* xb  = (_Float16*)(ws + 0);          // 16 MiB  [4096][2048]
  _Float16* wqt = (_Float16*)(ws + 16777216);   // 24 MiB  [6144][2048]
  _Float16* wot = (_Float16*)(ws + 41943040);   // 8 MiB   [2048][2048]
  _Float16* q   = (_Float16*)(ws + 50331648);   // 16 MiB  [b,h,s,d]
  _Float16* k   = (_Float16*)(ws + 67108864);   // 16 MiB  [b,h,s,d]
  _Float16* vt  = (_Float16*)(ws + 83886080);   // 16 MiB  [b,h,d,s]
  _Float16* ctx = (_Float16*)(ws + 100663296);  // 16 MiB  [4096][2048]

  prep<<<6144, 256, 0, stream>>>(x, xb, qkv_w, wqt, out_w, wot);
  gemm_bt<0><<<dim3(48, 32), 256, 0, stream>>>(xb, wqt, qkv_b, 2048, q, k, vt, nullptr, 6144);
  attn_kernel<<<dim3(32, 16), 256, 0, stream>>>(q, k, vt, ctx);
  gemm_bt<1><<<dim3(16, 32), 256, 0, stream>>>(ctx, wot, out_b, 2048, nullptr, nullptr, nullptr,
                                               out, 2048);
}

// Round 11
// 358.735 us; speedup vs baseline: 1.0951x; 1.0300x over previous
//
#include <hip/hip_runtime.h>

typedef _Float16 h8 __attribute__((ext_vector_type(8)));
typedef _Float16 h4 __attribute__((ext_vector_type(4)));
typedef float f4 __attribute__((ext_vector_type(4)));

#define MFMA16(a, b, c) __builtin_amdgcn_mfma_f32_16x16x32_f16((a), (b), (c), 0, 0, 0)
#define AS1 __attribute__((address_space(1)))
#define AS3 __attribute__((address_space(3)))

static __device__ __forceinline__ void load_lds16(const _Float16* g, _Float16* l) {
  // async DMA: 16B per lane, LDS dest = wave-uniform base + lane*16 [m97]
  __builtin_amdgcn_global_load_lds((const AS1 void*)g, (AS3 void*)l, 16, 0, 0);
}

// ---------------- fused prep: qkv_w transpose | out_w transpose | x convert ----------------
static __device__ __forceinline__ void tr_tile(const float* __restrict__ W,
                                               _Float16* __restrict__ Wt, int K, int N, int n0,
                                               int k0, int tid, _Float16 (*t)[66]) {
  const int c = tid & 63, r0_ = tid >> 6;
#pragma unroll
  for (int i = 0; i < 16; i++) {
    int r = r0_ * 16 + i;
    t[r][c] = (_Float16)W[(size_t)(k0 + r) * N + n0 + c];
  }
  __syncthreads();
  const int x8 = tid & 7, nl = tid >> 3;  // k-chunk, n-row
#pragma unroll
  for (int i = 0; i < 2; i++) {
    const int n = nl + 32 * i;
    h8 v;
#pragma unroll
    for (int j = 0; j < 8; j++) v[j] = t[x8 * 8 + j][n];
    *(h8*)(&Wt[(size_t)(n0 + n) * K + k0 + x8 * 8]) = v;
  }
}

__global__ __launch_bounds__(256) void prep(const float* __restrict__ x,
                                            _Float16* __restrict__ xb,
                                            const float* __restrict__ qkv_w,
                                            _Float16* __restrict__ wqt,
                                            const float* __restrict__ out_w,
                                            _Float16* __restrict__ wot) {
  __shared__ _Float16 t[64][66];
  const int bid = blockIdx.x, tid = threadIdx.x;
  if (bid < 3072) {  // qkv_w [2048][6144] -> wqt [6144][2048]
    tr_tile(qkv_w, wqt, 2048, 6144, (bid % 96) * 64, (bid / 96) * 64, tid, t);
  } else if (bid < 4096) {  // out_w [2048][2048] -> wot [2048][2048]
    const int b2 = bid - 3072;
    tr_tile(out_w, wot, 2048, 2048, (b2 & 31) * 64, (b2 >> 5) * 64, tid, t);
  } else {  // x convert: 8388608 floats = 2097152 float4, blocks 4096..6143 x 1024 each
    const size_t base = (size_t)(bid - 4096) * 1024;
#pragma unroll
    for (int u = 0; u < 4; u++) {
      const size_t i4 = base + u * 256 + tid;
      const float4 v = *(const float4*)(x + i4 * 4);
      h4 o;
      o[0] = (_Float16)v.x; o[1] = (_Float16)v.y; o[2] = (_Float16)v.z; o[3] = (_Float16)v.w;
      *(h4*)(xb + i4 * 4) = o;
    }
  }
}

// ---------------- GEMM (BK=64, async double-buffered): C = A @ Bt^T + bias ----------------
// r0-exact (best measured: 110 us, MfmaUtil 43%, ~0 conflicts). Single barrier per K-iter:
// DMA for tile k+1 issued right after the barrier into the back buffer; latency hidden by
// tile k's 32 MFMAs; drain lands at the NEXT barrier. 2 blocks/CU -> decoupled barrier
// domains (m114 overlap). XOR chunk swizzle (proven 0 conflicts). MODE 0: QKV scatter via
// LDS bounce; MODE 1: fp32 out.
template <int MODE>
__global__ __launch_bounds__(256, 2) void gemm_bt(const _Float16* __restrict__ A,
                                               const _Float16* __restrict__ Bt,
                                               const float* __restrict__ bias, int K,
                                               _Float16* __restrict__ qp, _Float16* __restrict__ kp,
                                               _Float16* __restrict__ vtp, float* __restrict__ outp,
                                               int N) {
  __shared__ _Float16 LDS[2][16384];  // [buf][ As 8192 | Bs 8192 ], 64 KB total
  const int m0 = blockIdx.y * 128, n0 = blockIdx.x * 128;
  const int tid = threadIdx.x;
  const int w = tid >> 6, lane = tid & 63, quad = lane >> 4, l16 = lane & 15;
  const int wm = (w >> 1) * 64, wn = (w & 1) * 64;

  const int lc8 = (((lane & 7) ^ (lane >> 3)) * 8);  // swizzled k-offset (f16)
  const int rb = w * 32 + (lane >> 3);
  const _Float16* ap0 = A + (size_t)(m0 + rb) * K + lc8;
  const _Float16* bp0 = Bt + (size_t)(n0 + rb) * K + lc8;

  f4 acc[4][4] = {};
  // prologue: stage k=0 into buf 0
#pragma unroll
  for (int i = 0; i < 4; i++) {
    load_lds16(ap0 + (size_t)(i * 8) * K, &LDS[0][w * 2048 + i * 512]);
    load_lds16(bp0 + (size_t)(i * 8) * K, &LDS[0][8192 + w * 2048 + i * 512]);
  }
  for (int k0 = 0; k0 < K; k0 += 64) {
    const int cur = (k0 >> 6) & 1;
    __syncthreads();  // buf[cur] DMA drained (all waves) + prev readers of buf[cur^1] done
    if (k0 + 64 < K) {
      const int nb = cur ^ 1;
#pragma unroll
      for (int i = 0; i < 4; i++) {
        load_lds16(ap0 + (size_t)(i * 8) * K + k0 + 64, &LDS[nb][w * 2048 + i * 512]);
        load_lds16(bp0 + (size_t)(i * 8) * K + k0 + 64, &LDS[nb][8192 + w * 2048 + i * 512]);
      }
    }
    const _Float16* As = &LDS[cur][0];
    const _Float16* Bs = &LDS[cur][8192];
#pragma unroll
    for (int ks = 0; ks < 2; ks++) {
      h8 af[4], bf[4];
      for (int mi = 0; mi < 4; mi++) {
        int r = wm + mi * 16 + l16;
        int pc = (ks * 4 + quad) ^ (l16 & 7);
        af[mi] = *(const h8*)(&As[r * 64 + pc * 8]);
      }
      for (int ni = 0; ni < 4; ni++) {
        int r = wn + ni * 16 + l16;
        int pc = (ks * 4 + quad) ^ (l16 & 7);
        bf[ni] = *(const h8*)(&Bs[r * 64 + pc * 8]);
      }
      for (int mi = 0; mi < 4; mi++)
        for (int ni = 0; ni < 4; ni++) acc[mi][ni] = MFMA16(af[mi], bf[ni], acc[mi][ni]);
    }
  }

  // ---- Epilogue. C element (row = quad*4+r, col = l16) per 16x16 tile [m89-verified]. ----
  if constexpr (MODE == 0) {
    __syncthreads();
    _Float16* U = &LDS[0][0];  // 128 x 136 bounce tile (34816 B <= 64 KB)
    const int which = n0 >> 11, hh = (n0 >> 7) & 15;
    const int bq = m0 >> 11, ms = m0 & 2047;
    const size_t hb = (size_t)bq * 16 + hh;
    if (which == 2) {
      for (int mi = 0; mi < 4; mi++)
        for (int ni = 0; ni < 4; ni++) {
          int d = wn + ni * 16 + l16;
          int s0 = wm + mi * 16 + quad * 4;
          float bv = bias[n0 + d];
          h4 pack;
          for (int r = 0; r < 4; r++) pack[r] = (_Float16)(acc[mi][ni][r] + bv);
          *(h4*)(&U[d * 136 + s0]) = pack;
        }
    } else {
      for (int mi = 0; mi < 4; mi++)
        for (int ni = 0; ni < 4; ni++) {
          int d = wn + ni * 16 + l16;
          float bv = bias[n0 + d];
          for (int r = 0; r < 4; r++) {
            int s = wm + mi * 16 + quad * 4 + r;
            U[s * 136 + d] = (_Float16)(acc[mi][ni][r] + bv);
          }
        }
    }
    __syncthreads();
    if (which == 2) {
      _Float16* dst = vtp + hb * (size_t)(128 * 2048) + ms;
#pragma unroll
      for (int i = 0; i < 8; i++) {
        int f = i * 256 + tid, row = f >> 4, ch = f & 15;
        *(h8*)(dst + (size_t)row * 2048 + ch * 8) = *(h8*)(&U[row * 136 + ch * 8]);
      }
    } else {
      _Float16* dst = (which == 0 ? qp : kp) + (hb * 2048 + ms) * (size_t)128;
#pragma unroll
      for (int i = 0; i < 8; i++) {
        int f = i * 256 + tid, row = f >> 4, ch = f & 15;
        *(h8*)(dst + (size_t)row * 128 + ch * 8) = *(h8*)(&U[row * 136 + ch * 8]);
      }
    }
  } else {
    for (int mi = 0; mi < 4; mi++)
      for (int ni = 0; ni < 4; ni++) {
        int gm_base = m0 + wm + mi * 16 + quad * 4;
        int gn = n0 + wn + ni * 16 + l16;
        float bv = bias[gn];
        for (int r = 0; r < 4; r++)
          outp[(size_t)(gm_base + r) * N + gn] = acc[mi][ni][r] + bv;
      }
  }
}

// ---------------- fused causal ALiBi attention ----------------
// grid (32 bh, 16 px): 512 uniform blocks (2/CU, 2 waves/SIMD); same-(b,h) blocks share an
// XCD (linear id mod 8 = bh mod 8) so K/V re-reads hit that XCD's L2.
// Block: 4 waves x 16 q-rows = 64-row tile; pairs {31-px, px} -> 33 j-iters each.
// K/V async-DMA double-buffered (1 barrier/iter, latency hidden under compute).
// ALiBi as column bias slope*j (row term -slope*i cancels in softmax); causal mask only on
// the diagonal tile. Row-sum l via a ones-column MFMA tile (o[8]).
__global__ __launch_bounds__(256, 2) void attn_kernel(const _Float16* __restrict__ Q,
                                                      const _Float16* __restrict__ Kg,
                                                      const _Float16* __restrict__ Vt,
                                                      _Float16* __restrict__ ctx) {
  __shared__ _Float16 Ks[2][8192];   // 64 rows x 128, 16B-chunk XOR swizzle p = lc ^ (row&7)
  __shared__ _Float16 Vs[2][8192];   // 128 rows x 64, same swizzle
  __shared__ _Float16 Vones[1088];   // [16][68]: row 0 = ones (l-accumulator B-tile)
  __shared__ _Float16 Pl[4][16 * 68];  // per-wave P round-trip; stride 68 -> conflict-free

  const int bh = blockIdx.x, px = blockIdx.y;
  const int b = bh >> 4, h = bh & 15;
  const int tid = threadIdx.x, w = tid >> 6, lane = tid & 63, quad = lane >> 4, l16 = lane & 15;
  const size_t hbo = (size_t)bh * (2048 * 128);
  const _Float16* Qh = Q + hbo;
  const _Float16* Kh = Kg + hbo;
  const _Float16* Vh = Vt + hbo;
  const float slope = exp2f(-0.5f * (float)h);
  const float L2E = 1.44269504088896f;
  const float NEG = -3.0e38f;

  for (int i = tid; i < 1088; i += 256) Vones[i] = (_Float16)0.f;
  if (tid < 64) Vones[tid] = (_Float16)1.f;  // row 0, cols 0..63

  float cj[4];
  for (int jf = 0; jf < 4; jf++) cj[jf] = slope * (float)(jf * 16 + l16);

  // staging constants: K slot s=c*64+lane -> row=4c+quad, lc=l16^((c&1)*4+quad)
  //                    V slot s=c*64+lane -> row=8c+(lane>>3), lc=(lane&7)^(lane>>3)
  const int kle = (l16 ^ quad) * 8, klo = kle ^ 32;
  const int lq = lane >> 3, vlc = ((lane & 7) ^ lq) * 8;

  for (int phase = 0; phase < 2; phase++) {
    const int t = phase ? px : 31 - px;
    const int qbase = t * 64 + w * 16;

    h8 aq[4];  // Q A-frags: A[m=l16][k=quad*8+j] [m120-verified]
#pragma unroll
    for (int t4 = 0; t4 < 4; t4++)
      aq[t4] = *(const h8*)(Qh + (size_t)(qbase + l16) * 128 + t4 * 32 + quad * 8);

    f4 o[9] = {};  // o[0..7] = output tiles, o[8] = row-sum (ones column)
    float m_i[4];
    for (int r = 0; r < 4; r++) m_i[r] = NEG;

    const int jtiles = t + 1;
    __syncthreads();  // previous phase's buffer readers (and Vones init) done
    // stage tile 0 -> buf 0 (waves 0,1: K; waves 2,3: V)
    if (w < 2) {
      const _Float16* kb = Kh + (size_t)(32 * w + quad) * 128;
      _Float16* dst = &Ks[0][w * 4096];
#pragma unroll
      for (int cc = 0; cc < 8; cc++)
        load_lds16(kb + (size_t)(4 * cc) * 128 + ((cc & 1) ? klo : kle), dst + cc * 512);
    } else {
      const _Float16* vb = Vh + (size_t)(64 * (w - 2) + lq) * 2048 + vlc;
      _Float16* dst = &Vs[0][(w - 2) * 4096];
#pragma unroll
      for (int cc = 0; cc < 8; cc++) load_lds16(vb + (size_t)(8 * cc) * 2048, dst + cc * 512);
    }

    for (int jt = 0; jt < jtiles; jt++) {
      const int j0 = jt * 64, cur = jt & 1;
      __syncthreads();  // buf[cur] staged (each wave drains vmcnt before barrier)
      if (jt + 1 < jtiles) {  // async-stage next tile into back buffer
        const int nj0 = j0 + 64, nb = cur ^ 1;
        if (w < 2) {
          const _Float16* kb = Kh + (size_t)(nj0 + 32 * w + quad) * 128;
          _Float16* dst = &Ks[nb][w * 4096];
#pragma unroll
          for (int cc = 0; cc < 8; cc++)
            load_lds16(kb + (size_t)(4 * cc) * 128 + ((cc & 1) ? klo : kle), dst + cc * 512);
        } else {
          const _Float16* vb = Vh + (size_t)(64 * (w - 2) + lq) * 2048 + nj0 + vlc;
          _Float16* dst = &Vs[nb][(w - 2) * 4096];
#pragma unroll
          for (int cc = 0; cc < 8; cc++) load_lds16(vb + (size_t)(8 * cc) * 2048, dst + cc * 512);
        }
      }
      // S = Q K^T (B-frag from swizzled Ks)
      f4 sc[4] = {};
#pragma unroll
      for (int jf = 0; jf < 4; jf++) {
        const int row = jf * 16 + l16;
#pragma unroll
        for (int t4 = 0; t4 < 4; t4++) {
          const int p = (t4 * 4 + quad) ^ (l16 & 7);
          h8 bk = *(const h8*)(&Ks[cur][row * 128 + p * 8]);
          sc[jf] = MFMA16(aq[t4], bk, sc[jf]);
        }
      }
      // ALiBi column bias
      const float bj0 = slope * (float)j0;
#pragma unroll
      for (int jf = 0; jf < 4; jf++) {
        const float cb = bj0 + cj[jf];
#pragma unroll
        for (int r = 0; r < 4; r++) sc[jf][r] += cb;
      }
      if (jt == jtiles - 1) {  // diagonal tile: causal mask
#pragma unroll
        for (int jf = 0; jf < 4; jf++) {
          const int j = j0 + jf * 16 + l16;
#pragma unroll
          for (int r = 0; r < 4; r++)
            if (j > qbase + quad * 4 + r) sc[jf][r] = NEG;
        }
      }
      // online softmax (max only; sum rides in o[8])
      float m_new[4], alpha[4];
#pragma unroll
      for (int r = 0; r < 4; r++) {
        float v = fmaxf(fmaxf(sc[0][r], sc[1][r]), fmaxf(sc[2][r], sc[3][r]));
        v = fmaxf(v, __shfl_xor(v, 1));
        v = fmaxf(v, __shfl_xor(v, 2));
        v = fmaxf(v, __shfl_xor(v, 4));
        v = fmaxf(v, __shfl_xor(v, 8));
        m_new[r] = fmaxf(m_i[r], v);
        alpha[r] = exp2f((m_i[r] - m_new[r]) * L2E);
        m_i[r] = m_new[r];
      }
#pragma unroll
      for (int jf = 0; jf < 4; jf++)
#pragma unroll
        for (int r = 0; r < 4; r++) sc[jf][r] = exp2f((sc[jf][r] - m_new[r]) * L2E);
#pragma unroll
      for (int nt = 0; nt < 9; nt++)
#pragma unroll
        for (int r = 0; r < 4; r++) o[nt][r] *= alpha[r];
      // P: C-layout -> A-layout via per-wave LDS (stride 68: conflict-free writes)
#pragma unroll
      for (int jf = 0; jf < 4; jf++)
#pragma unroll
        for (int r = 0; r < 4; r++)
          Pl[w][(quad * 4 + r) * 68 + jf * 16 + l16] = (_Float16)sc[jf][r];
      asm volatile("s_waitcnt lgkmcnt(0)" ::: "memory");
      h8 ap0 = *(const h8*)(&Pl[w][l16 * 68 + quad * 8]);
      h8 ap1 = *(const h8*)(&Pl[w][l16 * 68 + 32 + quad * 8]);
      // O += P V (B-frag from swizzled Vs) + ones-tile for l
#pragma unroll
      for (int nt = 0; nt < 8; nt++) {
        const int row = nt * 16 + l16;
        const int p0 = quad ^ (l16 & 7), p1 = (4 + quad) ^ (l16 & 7);
        h8 bv0 = *(const h8*)(&Vs[cur][row * 64 + p0 * 8]);
        h8 bv1 = *(const h8*)(&Vs[cur][row * 64 + p1 * 8]);
        o[nt] = MFMA16(ap0, bv0, o[nt]);
        o[nt] = MFMA16(ap1, bv1, o[nt]);
      }
      {
        h8 b0 = *(const h8*)(&Vones[l16 * 68 + quad * 8]);
        h8 b1 = *(const h8*)(&Vones[l16 * 68 + 32 + quad * 8]);
        o[8] = MFMA16(ap0, b0, o[8]);
        o[8] = MFMA16(ap1, b1, o[8]);
      }
    }

    // epilogue: l = o[8] col 0 (broadcast within quad), normalize, write ctx
#pragma unroll
    for (int r = 0; r < 4; r++) {
      float lsum = __shfl(o[8][r], lane & 48);
      float inv = 1.0f / lsum;
      const int i = qbase + quad * 4 + r;
      const size_t row = (size_t)b * 2048 + i;
#pragma unroll
      for (int nt = 0; nt < 8; nt++)
        ctx[row * 2048 + h * 128 + nt * 16 + l16] = (_Float16)(o[nt][r] * inv);
    }
  }
}

extern "C" void kernel_launch(void* const* d_in, const int* in_sizes, int n_in, void* d_out,
                              int out_size, void* d_ws, size_t ws_size, hipStream_t stream) {
  const float* x = (const float*)d_in[0];      // [2,2048,2048]
  const float* qkv_w = (const float*)d_in[1];  // [2048,6144]
  const float* qkv_b = (const float*)d_in[2];  // [6144]
  const float* out_w = (const float*)d_in[3];  // [2048,2048]
  const float* out_b = (const float*)d_in[4];  // [2048]
  float* out = (float*)d_out;                  // [4096,2048] f32

  char* ws = (char*)d_ws;
  if (ws_size < 117440512u) return;  // need 112 MiB
  _Float16* xb  = (_Float16*)(ws + 0);          // 16 MiB  [4096][2048]
  _Float16* wqt = (_Float16*)(ws + 16777216);   // 24 MiB  [6144][2048]
  _Float16* wot = (_Float16*)(ws + 41943040);   // 8 MiB   [2048][2048]
  _Float16* q   = (_Float16*)(ws + 50331648);   // 16 MiB  [b,h,s,d]
  _Float16* k   = (_Float16*)(ws + 67108864);   // 16 MiB  [b,h,s,d]
  _Float16* vt  = (_Float16*)(ws + 83886080);   // 16 MiB  [b,h,d,s]
  _Float16* ctx = (_Float16*)(ws + 100663296);  // 16 MiB  [4096][2048]

  prep<<<6144, 256, 0, stream>>>(x, xb, qkv_w, wqt, out_w, wot);
  gemm_bt<0><<<dim3(48, 32), 256, 0, stream>>>(xb, wqt, qkv_b, 2048, q, k, vt, nullptr, 6144);
  attn_kernel<<<dim3(32, 16), 256, 0, stream>>>(q, k, vt, ctx);
  gemm_bt<1><<<dim3(16, 32), 256, 0, stream>>>(ctx, wot, out_b, 2048, nullptr, nullptr, nullptr,
                                               out, 2048);
}